// Round 1
// 483.613 us; speedup vs baseline: 1.0023x; 1.0023x over previous
//
#include <hip/hip_runtime.h>
#include <stdint.h>

// y[row, 64k+m] = (1/48) * sum_j H36[k][j] * sum_l (-1)^popcount(m&l) * x[row, 64j+l]
// v2: ONE row per wave, lane = column within each 64-block (1 float per lane per j).
//   - 36 data VGPRs (was 72) + __launch_bounds__(256,8)  =>  8 waves/SIMD (2x occupancy)
//   - FWHT64: 6 xor-butterfly stages. Masks 1..16 via __shfl_xor (ds_swizzle, DS pipe),
//     mask 32 via v_permlane32_swap (VALU pipe) so DS-pipe load stays at 5 stages.
//   - H36 matmul: y[k] = (S - 2*N[k])/48 with compile-time NEG masks; rows with
//     popcount>18 use the complement form y[k] = (2*P[k] - S)/48 (fewer adds).

constexpr uint64_t neg_mask(const char* s) {
    uint64_t m = 0;
    for (int j = 0; j < 36; ++j)
        if (s[j] == '-') m |= (1ull << j);
    return m;
}

constexpr uint64_t NEG[36] = {
    neg_mask("++++++++++++++++++-+++++++++++++++++"),
    neg_mask("++++-+---++---+-+++-++-+---++---+-++"),
    neg_mask("+++++-+---++---+-+++-++-+---++---+-+"),
    neg_mask("++++++-+---++---+-+++-++-+---++---+-"),
    neg_mask("+-+++++-+---++---++-++-++-+---++---+"),
    neg_mask("++-+++++-+---++---++-++-++-+---++---"),
    neg_mask("+-+-+++++-+---++--+-+-++-++-+---++--"),
    neg_mask("+--+-+++++-+---++-+--+-++-++-+---++-"),
    neg_mask("+---+-+++++-+---+++---+-++-++-+---++"),
    neg_mask("++---+-+++++-+---+++---+-++-++-+---+"),
    neg_mask("+++---+-+++++-+---+++---+-++-++-+---"),
    neg_mask("+-++---+-+++++-+--+-++---+-++-++-+--"),
    neg_mask("+--++---+-+++++-+-+--++---+-++-++-+-"),
    neg_mask("+---++---+-+++++-++---++---+-++-++-+"),
    neg_mask("++---++---+-+++++-++---++---+-++-++-"),
    neg_mask("+-+---++---+-++++++-+---++---+-++-++"),
    neg_mask("++-+---++---+-++++++-+---++---+-++-+"),
    neg_mask("+++-+---++---+-++++++-+---++---+-++-"),
    neg_mask("-+++++++++++++++++------------------"),
    neg_mask("+-++-+---++---+-++----+-+++--+++-+--"),
    neg_mask("++-++-+---++---+-+-----+-+++--+++-+-"),
    neg_mask("+++-++-+---++---+-------+-+++--+++-+"),
    neg_mask("+-++-++-+---++---+-+-----+-+++--+++-"),
    neg_mask("++-++-++-+---++-----+-----+-+++--+++"),
    neg_mask("+-+-++-++-+---++---+-+-----+-+++--++"),
    neg_mask("+--+-++-++-+---++--++-+-----+-+++--+"),
    neg_mask("+---+-++-++-+---++-+++-+-----+-+++--"),
    neg_mask("++---+-++-++-+---+--+++-+-----+-+++-"),
    neg_mask("+++---+-++-++-+------+++-+-----+-+++"),
    neg_mask("+-++---+-++-++-+---+--+++-+-----+-++"),
    neg_mask("+--++---+-++-++-+--++--+++-+-----+-+"),
    neg_mask("+---++---+-++-++-+-+++--+++-+-----+-"),
    neg_mask("++---++---+-++-++---+++--+++-+-----+"),
    neg_mask("+-+---++---+-++-++-+-+++--+++-+-----"),
    neg_mask("++-+---++---+-++-+--+-+++--+++-+----"),
    neg_mask("+++-+---++---+-++----+-+++--+++-+---"),
};

#define ROWLEN 2304

__global__ __launch_bounds__(256, 8) void had_kernel(const float* __restrict__ x,
                                                     float* __restrict__ out,
                                                     int n_rows) {
    const int tid  = threadIdx.x;
    const int wave = tid >> 6;
    const int lane = tid & 63;

    const long long row = (long long)blockIdx.x * 4 + wave;
    if (row >= n_rows) return;

    const float* xr = x + row * (long long)ROWLEN + lane;

    float v[36];
#pragma unroll
    for (int j = 0; j < 36; ++j) v[j] = xr[j * 64];

    // FWHT64 butterfly stages for column bits 0..4 (within 32-lane halves:
    // these compile to single ds_swizzle ops).
#pragma unroll
    for (int p = 0; p < 5; ++p) {
        const int mask = 1 << p;
        const float s = (lane & mask) ? -1.0f : 1.0f;  // bit set: partner - v ; else v + partner
#pragma unroll
        for (int j = 0; j < 36; ++j) {
            float pv = __shfl_xor(v[j], mask, 64);
            v[j] = fmaf(v[j], s, pv);
        }
    }

    // Stage for column bit 5 (exchange across the 32-lane halves).
    {
        const float s = (lane & 32) ? -1.0f : 1.0f;
#if __has_builtin(__builtin_amdgcn_permlane32_swap)
        // v_permlane32_swap_b32: swaps vdst[32:63] <-> vsrc[0:31].
        // With both inputs = x: ret.x = {x_lo, x_lo}, ret.y = {x_hi, x_hi};
        // partner(lane) = x[lane^32] = hi ? ret.x : ret.y.  (VALU pipe, not DS.)
        const bool hi = (lane & 32) != 0;
        typedef unsigned int uint2v __attribute__((ext_vector_type(2)));
#pragma unroll
        for (int j = 0; j < 36; ++j) {
            unsigned int b = __float_as_uint(v[j]);
            uint2v r = __builtin_amdgcn_permlane32_swap(b, b, false, false);
            float pv = __uint_as_float(hi ? r.x : r.y);
            v[j] = fmaf(v[j], s, pv);
        }
#else
#pragma unroll
        for (int j = 0; j < 36; ++j) {
            float pv = __shfl_xor(v[j], 32, 64);
            v[j] = fmaf(v[j], s, pv);
        }
#endif
    }

    // S = sum over j (4-way partial tree for ILP)
    float s0 = 0.0f, s1 = 0.0f, s2 = 0.0f, s3 = 0.0f;
#pragma unroll
    for (int j = 0; j < 36; j += 4) {
        s0 += v[j];
        s1 += v[j + 1];
        s2 += v[j + 2];
        s3 += v[j + 3];
    }
    const float S = (s0 + s1) + (s2 + s3);

    const float S48   = S * (1.0f / 48.0f);
    const float mS48  = -S48;
    const float c_neg = -2.0f / 48.0f;
    const float c_pos =  2.0f / 48.0f;

    float* yr = out + row * (long long)ROWLEN + lane;

    // y[k] = S/48 - (2/48)*N[k]   (N[k] = sum over negative H36 entries), or the
    // complement form y[k] = (2/48)*P[k] - S/48 when the row has >18 negatives.
    // All masks/popcounts fold at compile time under full unroll.
#pragma unroll
    for (int k = 0; k < 36; ++k) {
        const uint64_t m  = NEG[k];
        const int      pc = __builtin_popcountll(m);
        const uint64_t msel = (pc <= 18) ? m : (~m & ((1ull << 36) - 1));
        float acc = 0.0f;
#pragma unroll
        for (int j = 0; j < 36; ++j) {
            if ((msel >> j) & 1) acc += v[j];
        }
        const float y = (pc <= 18) ? fmaf(acc, c_neg, S48) : fmaf(acc, c_pos, mS48);
        yr[k * 64] = y;
    }
}

extern "C" void kernel_launch(void* const* d_in, const int* in_sizes, int n_in,
                              void* d_out, int out_size, void* d_ws, size_t ws_size,
                              hipStream_t stream) {
    const float* x = (const float*)d_in[0];
    float* out = (float*)d_out;
    const int n_rows = in_sizes[0] / ROWLEN;          // 32768
    const int rows_per_block = 4;                     // 4 waves x 1 row
    const int grid = (n_rows + rows_per_block - 1) / rows_per_block;
    hipLaunchKernelGGL(had_kernel, dim3(grid), dim3(256), 0, stream, x, out, n_rows);
}